// Round 2
// baseline (629.597 us; speedup 1.0000x reference)
//
#include <hip/hip_runtime.h>
#include <math.h>

#define SC 4
#define BB 2
#define CC 32
#define HH 256
#define WW 512
#define CH (HH / SC)   // 64
#define CW (WW / SC)   // 128

// Direction metadata (output channel order: c, l, r, t, b, lt, rt, lb, rb)
// dh/dw: coarse-cell (and /4 pixel) offsets. s0/s1: distance-channel selector.
//   s0: 0 -> xv (x[w%4]), 1 -> 4-(w%4) (D1), 2 -> (w%4)+1 (D2)
//   s1: 0 -> yv (x[h%4]), 1 -> 4-(h%4) (D3), 2 -> (h%4)+1 (D4)
// NOTE: diagonals reuse D1..D4 which modify ONLY ONE channel each:
//   lt->D1 (ch0=x1, ch1=yv), rt->D2 (ch0=x2, ch1=yv),
//   lb->D3 (ch0=xv, ch1=y1), rb->D4 (ch0=xv, ch1=y2).
__device__ __constant__ int c_dh[9] = {0, 0, 0, -1, 1, -1, -1, 1, 1};
__device__ __constant__ int c_dw[9] = {0, -1, 1, 0, 0, -1, 1, -1, 1};
__device__ __constant__ int c_s0[9] = {0, 1, 2, 0, 0, 1, 2, 0, 0};
__device__ __constant__ int c_s1[9] = {0, 0, 0, 1, 2, 0, 0, 1, 2};

// Pre-pass: ALr[(b*CH+cy)*CW+cx][o] = sum_c w0[o*66+c] * lr[b][c][cy][cx]
__global__ __launch_bounds__(256) void alr_prepass(const float* __restrict__ lr,
                                                   const float* __restrict__ w0,
                                                   float* __restrict__ alr) {
    const int idx = blockIdx.x * 256 + threadIdx.x;  // over BB*CH*CW = 16384
    if (idx >= BB * CH * CW) return;
    const int b = idx / (CH * CW);
    const int cell = idx - b * (CH * CW);
    const float* lp = lr + (size_t)b * CC * CH * CW + cell;
    float lv[32];
#pragma unroll
    for (int c = 0; c < 32; c++) lv[c] = lp[(size_t)c * (CH * CW)];
    float acc[32];
#pragma unroll
    for (int o = 0; o < 32; o++) {
        float a = 0.f;
#pragma unroll
        for (int c = 0; c < 32; c++) a = fmaf(lv[c], w0[o * 66 + c], a);
        acc[o] = a;
    }
    float4* op = (float4*)(alr + (size_t)idx * 32);
#pragma unroll
    for (int j = 0; j < 8; j++)
        op[j] = make_float4(acc[4 * j], acc[4 * j + 1], acc[4 * j + 2], acc[4 * j + 3]);
}

// Main: one thread per hr pixel; block covers a 4(h) x 64(w) tile.
template <bool USE_WS>
__global__ __launch_bounds__(256) void ercm_main(const float* __restrict__ hr,
                                                 const float* __restrict__ lr,
                                                 const float* __restrict__ alr,
                                                 const float* __restrict__ w0,
                                                 const float* __restrict__ w1,
                                                 const float* __restrict__ w2,
                                                 const float* __restrict__ w3,
                                                 float* __restrict__ out) {
    // 3 coarse rows x 18 coarse cols of 32-float ALr vectors, padded to 36
    // floats/cell (stride-32 would be a 16-way bank conflict on ds_read_b128;
    // 36 rotates 4 banks/cell -> 2-way, which is free).
    __shared__ float s_alr[54 * 36];
    __shared__ float s_lg[9 * 256];  // per-direction logits, conflict-free layout

    const int tid = threadIdx.x;
    const int bx = blockIdx.x;  // 0..7   (WW/64)
    const int by = blockIdx.y;  // 0..63  (HH/4)
    const int b = blockIdx.z;   // 0..1
    const int cy0 = by, cx0 = bx * 16;

    if (USE_WS) {
        for (int i = tid; i < 54 * 32; i += 256) {
            const int c = i & 31, cell = i >> 5;
            const int row = cell / 18, col = cell - row * 18;
            const int gcy = cy0 - 1 + row, gcx = cx0 - 1 + col;
            float v = 0.f;
            if ((unsigned)gcy < (unsigned)CH && (unsigned)gcx < (unsigned)CW)
                v = alr[(((size_t)b * CH + gcy) * CW + gcx) * 32 + c];
            s_alr[cell * 36 + c] = v;
        }
    } else {
        // Fallback if workspace too small: compute ALr tile in-block.
        for (int i = tid; i < 54 * 32; i += 256) {
            const int o = i & 31, cell = i >> 5;
            const int row = cell / 18, col = cell - row * 18;
            const int gcy = cy0 - 1 + row, gcx = cx0 - 1 + col;
            float a = 0.f;
            if ((unsigned)gcy < (unsigned)CH && (unsigned)gcx < (unsigned)CW) {
                const float* lp = lr + (size_t)b * CC * CH * CW + (size_t)gcy * CW + gcx;
#pragma unroll
                for (int c = 0; c < 32; c++) a = fmaf(lp[(size_t)c * (CH * CW)], w0[o * 66 + c], a);
            }
            s_alr[cell * 36 + o] = a;
        }
    }
    __syncthreads();

    const int tx = tid & 63, ty = tid >> 6;
    const int h = by * 4 + ty, w = bx * 64 + tx;
    const size_t HW = (size_t)HH * WW;

    // hr channel vector at the center pixel (shared by all 9 directions)
    float hrv[32];
    const float* hp = hr + (size_t)b * CC * HW + (size_t)h * WW + w;
#pragma unroll
    for (int c = 0; c < 32; c++) hrv[c] = hp[(size_t)c * HW];

    // A_hr[o] = sum_c hr[c] * w0[o, 32+c]  (weights come in as s_loads)
    float ahr[32];
#pragma unroll
    for (int o = 0; o < 32; o++) {
        float a = 0.f;
#pragma unroll
        for (int c = 0; c < 32; c++) a = fmaf(hrv[c], w0[o * 66 + 32 + c], a);
        ahr[o] = a;
    }

    const int xm = w & 3, ym = h & 3;
    const float xv = (float)(xm < 2 ? xm - 2 : xm - 1);  // x = [-2,-1,1,2]
    const float yv = (float)(ym < 2 ? ym - 2 : ym - 1);
    const float x1 = (float)(4 - xm), x2 = (float)(xm + 1);
    const float y1 = (float)(4 - ym), y2 = (float)(ym + 1);
    const int baseCell = (tx >> 2) + 1;  // local coarse col (+1 halo offset)

#pragma unroll 1  // keep rolled: ~800 VALU/iter stays in I-cache
    for (int d = 0; d < 9; d++) {
        const int dh = c_dh[d], dw = c_dw[d];
        const int sel0 = c_s0[d], sel1 = c_s1[d];
        const float d0 = (sel0 == 0) ? xv : ((sel0 == 1) ? x1 : x2);
        const float d1 = (sel1 == 0) ? yv : ((sel1 == 1) ? y1 : y2);
        const bool valid = ((unsigned)(h + 4 * dh) < (unsigned)HH) &&
                           ((unsigned)(w + 4 * dw) < (unsigned)WW);

        const float* ap = s_alr + ((1 + dh) * 18 + baseCell + dw) * 36;
        float v[32];
#pragma unroll
        for (int j = 0; j < 8; j++) {
            const float4 q = ((const float4*)ap)[j];
            v[4 * j + 0] = q.x; v[4 * j + 1] = q.y;
            v[4 * j + 2] = q.z; v[4 * j + 3] = q.w;
        }
        // layer 1: A_hr + A_lr + distance part, LeakyReLU(0.01)
#pragma unroll
        for (int o = 0; o < 32; o++) {
            float t = ahr[o] + v[o];
            t = fmaf(d0, w0[o * 66 + 64], t);
            t = fmaf(d1, w0[o * 66 + 65], t);
            v[o] = fmaxf(t, 0.01f * t);
        }
        // layer 2: 32 -> 16
        float h1[16];
#pragma unroll
        for (int o = 0; o < 16; o++) {
            float a = 0.f;
#pragma unroll
            for (int c = 0; c < 32; c++) a = fmaf(v[c], w1[o * 32 + c], a);
            h1[o] = fmaxf(a, 0.01f * a);
        }
        // layer 3: 16 -> 8
        float h2[8];
#pragma unroll
        for (int o = 0; o < 8; o++) {
            float a = 0.f;
#pragma unroll
            for (int c = 0; c < 16; c++) a = fmaf(h1[c], w2[o * 16 + c], a);
            h2[o] = fmaxf(a, 0.01f * a);
        }
        // layer 4: 8 -> 1 (no activation)
        float lg = 0.f;
#pragma unroll
        for (int c = 0; c < 8; c++) lg = fmaf(h2[c], w3[c], lg);

        s_lg[d * 256 + tid] = valid ? lg : -100.0f;
    }

    // softmax over the 9 direction logits
    float l[9];
#pragma unroll
    for (int d = 0; d < 9; d++) l[d] = s_lg[d * 256 + tid];
    float m = l[0];
#pragma unroll
    for (int d = 1; d < 9; d++) m = fmaxf(m, l[d]);
    float s = 0.f;
#pragma unroll
    for (int d = 0; d < 9; d++) {
        l[d] = expf(l[d] - m);
        s += l[d];
    }
    const float inv = 1.0f / s;
    float* op = out + (size_t)b * 9 * HW + (size_t)h * WW + w;
#pragma unroll
    for (int d = 0; d < 9; d++) op[(size_t)d * HW] = l[d] * inv;
}

extern "C" void kernel_launch(void* const* d_in, const int* in_sizes, int n_in,
                              void* d_out, int out_size, void* d_ws, size_t ws_size,
                              hipStream_t stream) {
    const float* lr = (const float*)d_in[0];
    const float* hr = (const float*)d_in[1];
    // d_in[2], d_in[3] (lr_feature_r / hr_feature_r) are unused by the reference.
    const float* w0 = (const float*)d_in[4];
    const float* w1 = (const float*)d_in[5];
    const float* w2 = (const float*)d_in[6];
    const float* w3 = (const float*)d_in[7];
    float* out = (float*)d_out;

    const size_t alr_bytes = (size_t)BB * CH * CW * 32 * sizeof(float);  // 2 MB
    dim3 grid(WW / 64, HH / 4, BB);  // 8 x 64 x 2 = 1024 blocks

    if (ws_size >= alr_bytes) {
        float* alr = (float*)d_ws;
        alr_prepass<<<(BB * CH * CW + 255) / 256, 256, 0, stream>>>(lr, w0, alr);
        ercm_main<true><<<grid, 256, 0, stream>>>(hr, lr, alr, w0, w1, w2, w3, out);
    } else {
        ercm_main<false><<<grid, 256, 0, stream>>>(hr, lr, nullptr, w0, w1, w2, w3, out);
    }
}

// Round 3
// 230.591 us; speedup vs baseline: 2.7304x; 2.7304x over previous
//
#include <hip/hip_runtime.h>
#include <math.h>

#define SC 4
#define BB 2
#define CC 32
#define HH 256
#define WW 512
#define CH (HH / SC)   // 64
#define CW (WW / SC)   // 128

// Direction metadata (output channel order: c, l, r, t, b, lt, rt, lb, rb)
// dh/dw: coarse-cell (and /4 pixel) offsets. s0/s1: distance-channel selector.
//   s0: 0 -> xv (x[w%4]), 1 -> 4-(w%4) (D1), 2 -> (w%4)+1 (D2)
//   s1: 0 -> yv (x[h%4]), 1 -> 4-(h%4) (D3), 2 -> (h%4)+1 (D4)
// NOTE: diagonals reuse D1..D4 which modify ONLY ONE channel each:
//   lt->D1 (ch0=x1, ch1=yv), rt->D2 (ch0=x2, ch1=yv),
//   lb->D3 (ch0=xv, ch1=y1), rb->D4 (ch0=xv, ch1=y2).
__device__ __constant__ int c_dh[9] = {0, 0, 0, -1, 1, -1, -1, 1, 1};
__device__ __constant__ int c_dw[9] = {0, -1, 1, 0, 0, -1, 1, -1, 1};
__device__ __constant__ int c_s0[9] = {0, 1, 2, 0, 0, 1, 2, 0, 0};
__device__ __constant__ int c_s1[9] = {0, 0, 0, 1, 2, 0, 0, 1, 2};

// Pre-pass: ALr[(b*CH+cy)*CW+cx][o] = sum_c w0[o*66+c] * lr[b][c][cy][cx]
__global__ __launch_bounds__(256) void alr_prepass(const float* __restrict__ lr,
                                                   const float* __restrict__ w0,
                                                   float* __restrict__ alr) {
    const int idx = blockIdx.x * 256 + threadIdx.x;  // over BB*CH*CW = 16384
    if (idx >= BB * CH * CW) return;
    const int b = idx / (CH * CW);
    const int cell = idx - b * (CH * CW);
    const float* lp = lr + (size_t)b * CC * CH * CW + cell;
    float lv[32];
#pragma unroll
    for (int c = 0; c < 32; c++) lv[c] = lp[(size_t)c * (CH * CW)];
    float acc[32];
#pragma unroll
    for (int o = 0; o < 32; o++) {
        float a = 0.f;
#pragma unroll
        for (int c = 0; c < 32; c++) a = fmaf(lv[c], w0[o * 66 + c], a);
        acc[o] = a;
    }
    float4* op = (float4*)(alr + (size_t)idx * 32);
#pragma unroll
    for (int j = 0; j < 8; j++)
        op[j] = make_float4(acc[4 * j], acc[4 * j + 1], acc[4 * j + 2], acc[4 * j + 3]);
}

// Main: one thread per hr pixel; block covers a 4(h) x 64(w) tile.
// __launch_bounds__(256, 4): 4 waves/EU -> 128-VGPR cap. Peak live state is
// ~100 VGPRs (ahr[32]+v[32]+h1[16]+scalars); the compiler's default budget
// was 72 which spilled the arrays to scratch (R2: 538us, occupancy 28%).
template <bool USE_WS>
__global__ __launch_bounds__(256, 4) void ercm_main(const float* __restrict__ hr,
                                                    const float* __restrict__ lr,
                                                    const float* __restrict__ alr,
                                                    const float* __restrict__ w0,
                                                    const float* __restrict__ w1,
                                                    const float* __restrict__ w2,
                                                    const float* __restrict__ w3,
                                                    float* __restrict__ out) {
    // 3 coarse rows x 18 coarse cols of 32-float ALr vectors, padded to 36
    // floats/cell (stride-32 would be a 16-way bank conflict on ds_read_b128;
    // 36 rotates 4 banks/cell -> 2-way, which is free).
    __shared__ float s_alr[54 * 36];
    __shared__ float s_lg[9 * 256];  // per-direction logits (d is runtime in
                                     // the rolled loop; LDS avoids a scratch
                                     // array / cndmask tree for l[d])

    const int tid = threadIdx.x;
    const int bx = blockIdx.x;  // 0..7   (WW/64)
    const int by = blockIdx.y;  // 0..63  (HH/4)
    const int b = blockIdx.z;   // 0..1
    const int cy0 = by, cx0 = bx * 16;

    if (USE_WS) {
        for (int i = tid; i < 54 * 32; i += 256) {
            const int c = i & 31, cell = i >> 5;
            const int row = cell / 18, col = cell - row * 18;
            const int gcy = cy0 - 1 + row, gcx = cx0 - 1 + col;
            float v = 0.f;
            if ((unsigned)gcy < (unsigned)CH && (unsigned)gcx < (unsigned)CW)
                v = alr[(((size_t)b * CH + gcy) * CW + gcx) * 32 + c];
            s_alr[cell * 36 + c] = v;
        }
    } else {
        // Fallback if workspace too small: compute ALr tile in-block.
        for (int i = tid; i < 54 * 32; i += 256) {
            const int o = i & 31, cell = i >> 5;
            const int row = cell / 18, col = cell - row * 18;
            const int gcy = cy0 - 1 + row, gcx = cx0 - 1 + col;
            float a = 0.f;
            if ((unsigned)gcy < (unsigned)CH && (unsigned)gcx < (unsigned)CW) {
                const float* lp = lr + (size_t)b * CC * CH * CW + (size_t)gcy * CW + gcx;
#pragma unroll
                for (int c = 0; c < 32; c++) a = fmaf(lp[(size_t)c * (CH * CW)], w0[o * 66 + c], a);
            }
            s_alr[cell * 36 + o] = a;
        }
    }
    __syncthreads();

    const int tx = tid & 63, ty = tid >> 6;
    const int h = by * 4 + ty, w = bx * 64 + tx;
    const size_t HW = (size_t)HH * WW;

    // hr channel vector at the center pixel (shared by all 9 directions)
    float hrv[32];
    const float* hp = hr + (size_t)b * CC * HW + (size_t)h * WW + w;
#pragma unroll
    for (int c = 0; c < 32; c++) hrv[c] = hp[(size_t)c * HW];

    // A_hr[o] = sum_c hr[c] * w0[o, 32+c]  (weights come in as s_loads)
    float ahr[32];
#pragma unroll
    for (int o = 0; o < 32; o++) {
        float a = 0.f;
#pragma unroll
        for (int c = 0; c < 32; c++) a = fmaf(hrv[c], w0[o * 66 + 32 + c], a);
        ahr[o] = a;
    }

    const int xm = w & 3, ym = h & 3;
    const float xv = (float)(xm < 2 ? xm - 2 : xm - 1);  // x = [-2,-1,1,2]
    const float yv = (float)(ym < 2 ? ym - 2 : ym - 1);
    const float x1 = (float)(4 - xm), x2 = (float)(xm + 1);
    const float y1 = (float)(4 - ym), y2 = (float)(ym + 1);
    const int baseCell = (tx >> 2) + 1;  // local coarse col (+1 halo offset)

#pragma unroll 1  // keep rolled: ~850 VALU/iter; 9x unroll would blow I-cache
    for (int d = 0; d < 9; d++) {
        const int dh = c_dh[d], dw = c_dw[d];
        const int sel0 = c_s0[d], sel1 = c_s1[d];
        const float d0 = (sel0 == 0) ? xv : ((sel0 == 1) ? x1 : x2);
        const float d1 = (sel1 == 0) ? yv : ((sel1 == 1) ? y1 : y2);
        const bool valid = ((unsigned)(h + 4 * dh) < (unsigned)HH) &&
                           ((unsigned)(w + 4 * dw) < (unsigned)WW);

        const float* ap = s_alr + ((1 + dh) * 18 + baseCell + dw) * 36;
        float v[32];
#pragma unroll
        for (int j = 0; j < 8; j++) {
            const float4 q = ((const float4*)ap)[j];
            v[4 * j + 0] = q.x; v[4 * j + 1] = q.y;
            v[4 * j + 2] = q.z; v[4 * j + 3] = q.w;
        }
        // layer 1: A_hr + A_lr + distance part, LeakyReLU(0.01)
#pragma unroll
        for (int o = 0; o < 32; o++) {
            float t = ahr[o] + v[o];
            t = fmaf(d0, w0[o * 66 + 64], t);
            t = fmaf(d1, w0[o * 66 + 65], t);
            v[o] = fmaxf(t, 0.01f * t);
        }
        // layer 2: 32 -> 16
        float h1[16];
#pragma unroll
        for (int o = 0; o < 16; o++) {
            float a = 0.f;
#pragma unroll
            for (int c = 0; c < 32; c++) a = fmaf(v[c], w1[o * 32 + c], a);
            h1[o] = fmaxf(a, 0.01f * a);
        }
        // layer 3: 16 -> 8
        float h2[8];
#pragma unroll
        for (int o = 0; o < 8; o++) {
            float a = 0.f;
#pragma unroll
            for (int c = 0; c < 16; c++) a = fmaf(h1[c], w2[o * 16 + c], a);
            h2[o] = fmaxf(a, 0.01f * a);
        }
        // layer 4: 8 -> 1 (no activation)
        float lg = 0.f;
#pragma unroll
        for (int c = 0; c < 8; c++) lg = fmaf(h2[c], w3[c], lg);

        s_lg[d * 256 + tid] = valid ? lg : -100.0f;
    }

    // softmax over the 9 direction logits
    float l[9];
#pragma unroll
    for (int d = 0; d < 9; d++) l[d] = s_lg[d * 256 + tid];
    float m = l[0];
#pragma unroll
    for (int d = 1; d < 9; d++) m = fmaxf(m, l[d]);
    float s = 0.f;
#pragma unroll
    for (int d = 0; d < 9; d++) {
        l[d] = __expf(l[d] - m);
        s += l[d];
    }
    const float inv = __builtin_amdgcn_rcpf(s);
    float* op = out + (size_t)b * 9 * HW + (size_t)h * WW + w;
#pragma unroll
    for (int d = 0; d < 9; d++) op[(size_t)d * HW] = l[d] * inv;
}

extern "C" void kernel_launch(void* const* d_in, const int* in_sizes, int n_in,
                              void* d_out, int out_size, void* d_ws, size_t ws_size,
                              hipStream_t stream) {
    const float* lr = (const float*)d_in[0];
    const float* hr = (const float*)d_in[1];
    // d_in[2], d_in[3] (lr_feature_r / hr_feature_r) are unused by the reference.
    const float* w0 = (const float*)d_in[4];
    const float* w1 = (const float*)d_in[5];
    const float* w2 = (const float*)d_in[6];
    const float* w3 = (const float*)d_in[7];
    float* out = (float*)d_out;

    const size_t alr_bytes = (size_t)BB * CH * CW * 32 * sizeof(float);  // 2 MB
    dim3 grid(WW / 64, HH / 4, BB);  // 8 x 64 x 2 = 1024 blocks

    if (ws_size >= alr_bytes) {
        float* alr = (float*)d_ws;
        alr_prepass<<<(BB * CH * CW + 255) / 256, 256, 0, stream>>>(lr, w0, alr);
        ercm_main<true><<<grid, 256, 0, stream>>>(hr, lr, alr, w0, w1, w2, w3, out);
    } else {
        ercm_main<false><<<grid, 256, 0, stream>>>(hr, lr, nullptr, w0, w1, w2, w3, out);
    }
}